// Round 3
// baseline (420.686 us; speedup 1.0000x reference)
//
#include <hip/hip_runtime.h>
#include <hip/hip_bf16.h>

// ---------------- problem constants ----------------
#define D_DIM 2048
#define HE_DIM 1024
#define E_NUM 8
#define T_NUM 4096
#define TK_NUM 8192           // T * K (top-2)
#define TILE 128              // GEMM M/N tile
#define BK 64                 // GEMM K tile (two 16x16x32 MFMA deep -> 32 MFMA/barrier)
#define MAXROWS 9216          // TK + E*TILE padding
#define MAXMT 72              // max M-tiles: 64 + 8

// meta (int) layout in workspace — counters padded to 128 B (32 ints) so each
// expert's atomic counter lives on its own cache line.
#define M_CNT(e)  ((e) * 32)          // [0,256)   per-expert token count
#define M_FILL(e) (256 + (e) * 32)    // [256,512) atomic fill cursor
#define M_OFF  512                    // [8] padded row base per expert
#define M_NMT  520                    // [1] number of m-tiles
#define M_TE   528                    // [72] m-tile -> expert
#define M_TB   600                    // [72] m-tile -> global row base
#define M_TICKET 704                  // [1] gate last-block ticket
#define M_INTS 1024

typedef unsigned short u16;
typedef __attribute__((ext_vector_type(8))) short bf16x8;  // 8 bf16 in 4 VGPRs
typedef __attribute__((ext_vector_type(4))) float f32x4;

// workspace offsets (bytes)
// xb [0,16M) and wupb [16M,48M) are dead after k_up; slot [T][2][D] bf16 (33.5M)
// overlaps them (k_down/k_combine run strictly after k_up on the stream).
#define OFF_XB   ((size_t)0)                                     // [T][D] bf16  16 MB
#define OFF_WUPB (OFF_XB + (size_t)T_NUM * D_DIM * 2)            // [E][HE][D] bf16 32 MB
#define OFF_SLOT ((size_t)0)                                     // [T][2][D] bf16 33.5 MB (overlap)
#define OFF_WDNB (OFF_WUPB + (size_t)E_NUM * HE_DIM * D_DIM * 2) // [E][D][HE] bf16 32 MB
#define OFF_H    (OFF_WDNB + (size_t)E_NUM * D_DIM * HE_DIM * 2) // [MAXROWS][HE] bf16 18.9 MB
#define OFF_SCR  (OFF_H + (size_t)MAXROWS * HE_DIM * 2)          // [TK] f32 slot score
#define OFF_EIDX (OFF_SCR + (size_t)TK_NUM * 4)                  // [TK] int slot expert
#define OFF_RT   (OFF_EIDX + (size_t)TK_NUM * 4)                 // [MAXROWS] int row->slot id
#define OFF_RS   (OFF_RT + (size_t)MAXROWS * 4)                  // [MAXROWS] f32 row score
#define OFF_META (OFF_RS + (size_t)MAXROWS * 4)                  // ints

__device__ __forceinline__ u16 f2bf(float f) {
  unsigned u = __float_as_uint(f);
  u += 0x7FFFu + ((u >> 16) & 1u);   // round-to-nearest-even
  return (u16)(u >> 16);
}
__device__ __forceinline__ float bf_lo(unsigned u) { return __uint_as_float(u << 16); }
__device__ __forceinline__ float bf_hi(unsigned u) { return __uint_as_float(u & 0xFFFF0000u); }

__device__ __forceinline__ void gload16(const void* g, void* l) {
  // async global->LDS, 16B per lane; LDS dest = wave-uniform base + lane*16
  __builtin_amdgcn_global_load_lds((const __attribute__((address_space(1))) void*)g,
                                   (__attribute__((address_space(3))) void*)l,
                                   16, 0, 0);
}

// counted waits (T4): never drain vmcnt to 0 in the steady-state loop.
#define WAIT_VM4 asm volatile("s_waitcnt vmcnt(4)" ::: "memory")
#define WAIT_VM0 asm volatile("s_waitcnt vmcnt(0)" ::: "memory")
#define SBAR     { __builtin_amdgcn_s_barrier(); asm volatile("" ::: "memory"); }

// ---------------- f32 -> bf16 weight conversion + meta/rows init (one launch) ----------------
__global__ void k_cvt2(const float4* __restrict__ s1, const float4* __restrict__ s2,
                       ushort4* __restrict__ d1, ushort4* __restrict__ d2, int n4,
                       int* __restrict__ meta, int* __restrict__ rows_slot,
                       float* __restrict__ rowscore) {
  const int i0 = blockIdx.x * blockDim.x + threadIdx.x;
  if (i0 < M_INTS) meta[i0] = 0;
  if (i0 < MAXROWS) { rows_slot[i0] = -1; rowscore[i0] = 0.0f; }
  const int st = gridDim.x * blockDim.x;
  for (int i = i0; i < 2 * n4; i += st) {
    const float4* s = (i < n4) ? s1 : s2;
    ushort4* d = (i < n4) ? d1 : d2;
    int j = (i < n4) ? i : i - n4;
    float4 v = s[j];
    ushort4 o;
    o.x = f2bf(v.x); o.y = f2bf(v.y); o.z = f2bf(v.z); o.w = f2bf(v.w);
    d[j] = o;
  }
}

// ---------------- gate: Wg1 in LDS, LDS count histogram, padded global atomics ----------------
// Last block to finish (device ticket) also computes the offsets + tile map.
__global__ __launch_bounds__(256) void k_gate(
    const float4* __restrict__ x4, const float4* __restrict__ Wg1_4,
    const float* __restrict__ Wg2, ushort4* __restrict__ xb4,
    int* __restrict__ eidx, float* __restrict__ scr, int* __restrict__ meta) {
  __shared__ float4 wg1s[E_NUM * (D_DIM / 4)];   // 8*512*16B = 64 KB
  __shared__ int cnt_s[E_NUM];
  __shared__ int lastf;
  const int tid = threadIdx.x;
  if (tid < E_NUM) cnt_s[tid] = 0;
#pragma unroll
  for (int i = 0; i < 16; ++i) wg1s[tid + i * 256] = Wg1_4[tid + i * 256];
  __syncthreads();

  const int w = tid >> 6;
  const int lane = tid & 63;
  for (int j = 0; j < 4; ++j) {
    const int t = blockIdx.x * 16 + w * 4 + j;
    float acc[E_NUM];
#pragma unroll
    for (int e = 0; e < E_NUM; ++e) acc[e] = 0.f;
#pragma unroll
    for (int i = 0; i < 8; ++i) {
      const int c = lane + i * 64;                 // float4 index within row (0..511)
      float4 xv = x4[(size_t)t * 512 + c];
      ushort4 o;
      o.x = f2bf(xv.x); o.y = f2bf(xv.y); o.z = f2bf(xv.z); o.w = f2bf(xv.w);
      xb4[(size_t)t * 512 + c] = o;
#pragma unroll
      for (int e = 0; e < E_NUM; ++e) {
        float4 wv = wg1s[e * 512 + c];
        acc[e] += xv.x * wv.x + xv.y * wv.y + xv.z * wv.z + xv.w * wv.w;
      }
    }
#pragma unroll
    for (int e = 0; e < E_NUM; ++e) {
      float v = acc[e];
#pragma unroll
      for (int off = 32; off; off >>= 1) v += __shfl_xor(v, off, 64);
      acc[e] = v;
    }
    if (lane == 0) {
      float l1[E_NUM], lg[E_NUM];
#pragma unroll
      for (int e = 0; e < E_NUM; ++e) l1[e] = tanhf(acc[e]);
#pragma unroll
      for (int i = 0; i < E_NUM; ++i) {
        float s = 0.f;
#pragma unroll
        for (int e = 0; e < E_NUM; ++e) s += l1[e] * Wg2[i * E_NUM + e];
        lg[i] = s;
      }
      // stable top-2 (lowest index wins ties, like jax.lax.top_k)
      int i0 = 0; float v0 = lg[0];
#pragma unroll
      for (int i = 1; i < E_NUM; ++i) if (lg[i] > v0) { v0 = lg[i]; i0 = i; }
      int i1 = -1; float v1 = -3.4e38f;
#pragma unroll
      for (int i = 0; i < E_NUM; ++i) if (i != i0 && lg[i] > v1) { v1 = lg[i]; i1 = i; }
      float e1 = __expf(v1 - v0);
      float s0 = 1.f / (1.f + e1);
      float s1 = e1 * s0;
      eidx[t * 2] = i0; eidx[t * 2 + 1] = i1;
      scr[t * 2] = s0;  scr[t * 2 + 1] = s1;
      atomicAdd(&cnt_s[i0], 1);      // LDS atomic — block-local, cheap
      atomicAdd(&cnt_s[i1], 1);
    }
  }
  __syncthreads();
  if (tid < E_NUM) atomicAdd(&meta[M_CNT(tid)], cnt_s[tid]);  // 8/block, padded lines

  // ---- last-block-done: compute offsets + tile map ----
  if (tid == 0) {
    __threadfence();
    lastf = (atomicAdd(&meta[M_TICKET], 1) == (int)gridDim.x - 1);
  }
  __syncthreads();
  if (lastf && tid < 64) {
    const int l2 = tid;
    int cnt = (l2 < E_NUM) ? atomicAdd(&meta[M_CNT(l2)], 0) : 0;
    int tiles = (cnt + TILE - 1) / TILE;
    int pre = tiles;
#pragma unroll
    for (int off = 1; off < E_NUM; off <<= 1) {
      int v = __shfl_up(pre, off, 64);
      if (l2 >= off && l2 < E_NUM) pre += v;
    }
    int tb_excl = pre - tiles;               // exclusive prefix (valid lanes 0..7)
    if (l2 < E_NUM) meta[M_OFF + l2] = tb_excl * TILE;
    const int nmt = __shfl(pre, E_NUM - 1, 64);
    if (l2 == 0) meta[M_NMT] = nmt;
    int tb[E_NUM];
#pragma unroll
    for (int k = 0; k < E_NUM; ++k) tb[k] = __shfl(tb_excl, k, 64);
    for (int mt = l2; mt < nmt; mt += 64) {
      int e = 0;
#pragma unroll
      for (int k = 1; k < E_NUM; ++k) if (mt >= tb[k]) e = k;
      meta[M_TE + mt] = e;
      meta[M_TB + mt] = mt * TILE;           // tile bases are contiguous multiples of TILE
    }
  }
}

// ---------------- compaction: wave-aggregated fetch-add ----------------
__global__ void k_assign(const int* __restrict__ eidx, const float* __restrict__ scr,
                         int* __restrict__ meta, int* __restrict__ rows_slot,
                         float* __restrict__ rowscore) {
  int i = blockIdx.x * blockDim.x + threadIdx.x;
  const int lane = threadIdx.x & 63;
  int e = eidx[i];
  int pos = 0;
#pragma unroll
  for (int ex = 0; ex < E_NUM; ++ex) {
    unsigned long long m = __ballot(e == ex);
    if (e == ex) {
      int leader = __ffsll((long long)m) - 1;
      int rank = __popcll(m & ((1ull << lane) - 1ull));
      int b = 0;
      if (lane == leader) b = atomicAdd(&meta[M_FILL(ex)], __popcll(m));
      b = __shfl(b, leader, 64);
      pos = b + rank;
    }
  }
  int r = meta[M_OFF + e] + pos;
  rows_slot[r] = i;            // slot id (token = i>>1)
  rowscore[r] = scr[i];
}

// ---------------- grouped up-GEMM: h = silu(Xg @ Wup[e]^T + bup[e]) ----------------
// T4 counted-vmcnt pipeline: 3 LDS buffers, prefetch depth 2. The wait at the
// bottom of iteration t targets loads issued a FULL iteration earlier (tile
// t+1); tile t+2's 4 loads stay in flight across the raw s_barrier. vmcnt
// never drains to 0 in steady state (m218: counted-vs-drain0 = +38..73%).
__global__ __launch_bounds__(512) void k_up(
    const u16* __restrict__ xb, const u16* __restrict__ wupb,
    const float* __restrict__ bup, const int* __restrict__ meta,
    const int* __restrict__ rows_slot, u16* __restrict__ hbuf) {
  const int mt = blockIdx.y;
  if (mt >= meta[M_NMT]) return;
  const int e = meta[M_TE + mt];
  const int mbase = meta[M_TB + mt];
  const int nt = blockIdx.x;

  __shared__ u16 As[3][TILE * BK];   // 3 x 16 KB
  __shared__ u16 Bs[3][TILE * BK];   // 3 x 16 KB

  const int tid = threadIdx.x;
  const int lane = tid & 63;
  const int w = tid >> 6;                                // 0..7
  const int r0 = tid >> 3;                               // staged row 0..63
  const int cb = (((tid & 7) ^ (r0 & 7)) * 8);           // swizzled k-chunk

  const u16* gA[2];
  const u16* gB[2];
#pragma unroll
  for (int j = 0; j < 2; ++j) {
    int s = rows_slot[mbase + r0 + 64 * j]; if (s < 0) s = 0;
    gA[j] = xb + (size_t)(s >> 1) * D_DIM + cb;
    gB[j] = wupb + ((size_t)e * HE_DIM + nt * TILE + r0 + 64 * j) * D_DIM + cb;
  }

  const int wm = (w & 1) * 64;
  const int wn = (w >> 1) * 32;
  const int quad = lane >> 4;
  const int l16 = lane & 15;
  const int sw = l16 & 7;

  f32x4 acc[4][2] = {};

#define STAGE_UP(buf, k0) \
  { gload16(gA[0] + (k0), &As[buf][tid * 8]);        \
    gload16(gA[1] + (k0), &As[buf][tid * 8 + 4096]); \
    gload16(gB[0] + (k0), &Bs[buf][tid * 8]);        \
    gload16(gB[1] + (k0), &Bs[buf][tid * 8 + 4096]); }

  STAGE_UP(0, 0);
  STAGE_UP(1, BK);
  WAIT_VM4;                             // tile 0 resident (tile 1 in flight)
  SBAR;
  int cur = 0, nxt = 2;
  for (int k0 = 0; k0 < D_DIM; k0 += BK) {
    const bool pf = (k0 + 2 * BK < D_DIM);
    if (pf) STAGE_UP(nxt, k0 + 2 * BK);  // issue tile t+2
    const u16* pa0 = &As[cur][(wm + l16) * BK];
    const u16* pb0 = &Bs[cur][(wn + l16) * BK];
#pragma unroll
    for (int h = 0; h < 2; ++h) {
      const int off = ((h * 4 + quad) ^ sw) * 8;
      bf16x8 af[4], bfr[2];
#pragma unroll
      for (int i = 0; i < 4; ++i) af[i] = *(const bf16x8*)(pa0 + i * 16 * BK + off);
#pragma unroll
      for (int i = 0; i < 2; ++i) bfr[i] = *(const bf16x8*)(pb0 + i * 16 * BK + off);
#pragma unroll
      for (int mi = 0; mi < 4; ++mi)
#pragma unroll
        for (int ni = 0; ni < 2; ++ni)
          acc[mi][ni] = __builtin_amdgcn_mfma_f32_16x16x32_bf16(af[mi], bfr[ni], acc[mi][ni], 0, 0, 0);
    }
    if (pf) { WAIT_VM4; } else { WAIT_VM0; }   // tile t+1 resident; t+2 stays in flight
    SBAR;
    cur = (cur == 2) ? 0 : cur + 1;
    nxt = (nxt == 2) ? 0 : nxt + 1;
  }

#pragma unroll
  for (int mi = 0; mi < 4; ++mi) {
    const int m = wm + mi * 16 + quad * 4;
#pragma unroll
    for (int ni = 0; ni < 2; ++ni) {
      const int ng = nt * TILE + wn + ni * 16 + l16;
      const float bias = bup[e * HE_DIM + ng];
#pragma unroll
      for (int r = 0; r < 4; ++r) {
        float v = acc[mi][ni][r] + bias;
        v = v / (1.0f + __expf(-v));     // silu
        hbuf[(size_t)(mbase + m + r) * HE_DIM + ng] = f2bf(v);
      }
    }
  }
}

// ---------------- grouped down-GEMM: slot[s] = score * (h @ Wdown[e]^T + bdown[e]) ----------------
__global__ __launch_bounds__(512) void k_down(
    const u16* __restrict__ hbuf, const u16* __restrict__ wdnb,
    const float* __restrict__ bdown, const int* __restrict__ meta,
    const int* __restrict__ rows_slot, const float* __restrict__ rowscore,
    u16* __restrict__ slot) {
  const int mt = blockIdx.y;
  if (mt >= meta[M_NMT]) return;
  const int e = meta[M_TE + mt];
  const int mbase = meta[M_TB + mt];
  const int nt = blockIdx.x;

  __shared__ u16 As[3][TILE * BK];
  __shared__ u16 Bs[3][TILE * BK];

  const int tid = threadIdx.x;
  const int lane = tid & 63;
  const int w = tid >> 6;
  const int r0 = tid >> 3;
  const int cb = (((tid & 7) ^ (r0 & 7)) * 8);

  const u16* gA[2];
  const u16* gB[2];
#pragma unroll
  for (int j = 0; j < 2; ++j) {
    gA[j] = hbuf + (size_t)(mbase + r0 + 64 * j) * HE_DIM + cb;
    gB[j] = wdnb + ((size_t)e * D_DIM + nt * TILE + r0 + 64 * j) * HE_DIM + cb;
  }

  const int wm = (w & 1) * 64;
  const int wn = (w >> 1) * 32;
  const int quad = lane >> 4;
  const int l16 = lane & 15;
  const int sw = l16 & 7;

  f32x4 acc[4][2] = {};

#define STAGE_DN(buf, k0) \
  { gload16(gA[0] + (k0), &As[buf][tid * 8]);        \
    gload16(gA[1] + (k0), &As[buf][tid * 8 + 4096]); \
    gload16(gB[0] + (k0), &Bs[buf][tid * 8]);        \
    gload16(gB[1] + (k0), &Bs[buf][tid * 8 + 4096]); }

  STAGE_DN(0, 0);
  STAGE_DN(1, BK);
  WAIT_VM4;
  SBAR;
  int cur = 0, nxt = 2;
  for (int k0 = 0; k0 < HE_DIM; k0 += BK) {
    const bool pf = (k0 + 2 * BK < HE_DIM);
    if (pf) STAGE_DN(nxt, k0 + 2 * BK);
    const u16* pa0 = &As[cur][(wm + l16) * BK];
    const u16* pb0 = &Bs[cur][(wn + l16) * BK];
#pragma unroll
    for (int h = 0; h < 2; ++h) {
      const int off = ((h * 4 + quad) ^ sw) * 8;
      bf16x8 af[4], bfr[2];
#pragma unroll
      for (int i = 0; i < 4; ++i) af[i] = *(const bf16x8*)(pa0 + i * 16 * BK + off);
#pragma unroll
      for (int i = 0; i < 2; ++i) bfr[i] = *(const bf16x8*)(pb0 + i * 16 * BK + off);
#pragma unroll
      for (int mi = 0; mi < 4; ++mi)
#pragma unroll
        for (int ni = 0; ni < 2; ++ni)
          acc[mi][ni] = __builtin_amdgcn_mfma_f32_16x16x32_bf16(af[mi], bfr[ni], acc[mi][ni], 0, 0, 0);
    }
    if (pf) { WAIT_VM4; } else { WAIT_VM0; }
    SBAR;
    cur = (cur == 2) ? 0 : cur + 1;
    nxt = (nxt == 2) ? 0 : nxt + 1;
  }

#pragma unroll
  for (int mi = 0; mi < 4; ++mi) {
    const int m = wm + mi * 16 + quad * 4;
#pragma unroll
    for (int r = 0; r < 4; ++r) {
      const int rg = mbase + m + r;
      const int s = rows_slot[rg];
      const float sc = rowscore[rg];
      if (s < 0) continue;               // padding row
      u16* dst = slot + (size_t)s * D_DIM;
#pragma unroll
      for (int ni = 0; ni < 2; ++ni) {
        const int ng = nt * TILE + wn + ni * 16 + l16;
        float v = (acc[mi][ni][r] + bdown[e * D_DIM + ng]) * sc;
        dst[ng] = f2bf(v);
      }
    }
  }
}

// ---------------- combine: out[t] = slot[t][0] + slot[t][1] (fully coalesced) ----------------
__global__ __launch_bounds__(256) void k_combine(const u16* __restrict__ slot,
                                                 float* __restrict__ out) {
  int i = blockIdx.x * blockDim.x + threadIdx.x;   // one 16B chunk (8 bf16) per thread
  int t = i >> 8;                                  // D/8 = 256 chunks per token
  int c = i & 255;
  const uint4* p0 = (const uint4*)(slot + (size_t)(t * 2) * D_DIM) + c;
  const uint4* p1 = (const uint4*)(slot + (size_t)(t * 2 + 1) * D_DIM) + c;
  uint4 a = *p0, b = *p1;
  float4 o0, o1;
  o0.x = bf_lo(a.x) + bf_lo(b.x);  o0.y = bf_hi(a.x) + bf_hi(b.x);
  o0.z = bf_lo(a.y) + bf_lo(b.y);  o0.w = bf_hi(a.y) + bf_hi(b.y);
  o1.x = bf_lo(a.z) + bf_lo(b.z);  o1.y = bf_hi(a.z) + bf_hi(b.z);
  o1.z = bf_lo(a.w) + bf_lo(b.w);  o1.w = bf_hi(a.w) + bf_hi(b.w);
  float4* po = (float4*)(out + (size_t)t * D_DIM) + c * 2;
  po[0] = o0;
  po[1] = o1;
}

// ---------------- launcher ----------------
extern "C" void kernel_launch(void* const* d_in, const int* in_sizes, int n_in,
                              void* d_out, int out_size, void* d_ws, size_t ws_size,
                              hipStream_t stream) {
  const float* x     = (const float*)d_in[0];
  const float* Wg1   = (const float*)d_in[1];
  const float* Wg2   = (const float*)d_in[2];
  const float* Wup   = (const float*)d_in[3];
  const float* bup   = (const float*)d_in[4];
  const float* Wdown = (const float*)d_in[5];
  const float* bdown = (const float*)d_in[6];
  float* out = (float*)d_out;

  char* ws = (char*)d_ws;
  u16*   xb         = (u16*)(ws + OFF_XB);
  u16*   wupb       = (u16*)(ws + OFF_WUPB);
  u16*   wdnb       = (u16*)(ws + OFF_WDNB);
  u16*   hbuf       = (u16*)(ws + OFF_H);
  u16*   slotbuf    = (u16*)(ws + OFF_SLOT);
  float* scr        = (float*)(ws + OFF_SCR);
  int*   eidx       = (int*)(ws + OFF_EIDX);
  int*   rows_slot  = (int*)(ws + OFF_RT);
  float* rowscore   = (float*)(ws + OFF_RS);
  int*   meta       = (int*)(ws + OFF_META);

  k_cvt2<<<8192, 256, 0, stream>>>((const float4*)Wup, (const float4*)Wdown,
                                   (ushort4*)wupb, (ushort4*)wdnb,
                                   E_NUM * HE_DIM * D_DIM / 4,
                                   meta, rows_slot, rowscore);
  k_gate<<<T_NUM / 16, 256, 0, stream>>>((const float4*)x, (const float4*)Wg1, Wg2,
                                         (ushort4*)xb, eidx, scr, meta);
  k_assign<<<TK_NUM / 256, 256, 0, stream>>>(eidx, scr, meta, rows_slot, rowscore);
  k_up<<<dim3(HE_DIM / TILE, MAXMT), 512, 0, stream>>>(xb, wupb, bup, meta, rows_slot, hbuf);
  k_down<<<dim3(D_DIM / TILE, MAXMT), 512, 0, stream>>>(hbuf, wdnb, bdown, meta,
                                                        rows_slot, rowscore, slotbuf);
  k_combine<<<T_NUM * D_DIM / 8 / 256, 256, 0, stream>>>(slotbuf, out);
}

// Round 5
// 403.095 us; speedup vs baseline: 1.0436x; 1.0436x over previous
//
#include <hip/hip_runtime.h>
#include <hip/hip_bf16.h>

// ---------------- problem constants ----------------
#define D_DIM 2048
#define HE_DIM 1024
#define E_NUM 8
#define T_NUM 4096
#define TK_NUM 8192           // T * K (top-2)
#define TILE 128              // GEMM M/N tile
#define BK 32                 // GEMM K tile (16 MFMA/wave per step; 48 KB for 3 bufs)
#define MAXROWS 9216          // TK + E*TILE padding
#define MAXMT 72              // max M-tiles: 64 + 8

// meta (int) layout in workspace — counters padded to 128 B (32 ints) so each
// expert's atomic counter lives on its own cache line.
#define M_CNT(e)  ((e) * 32)          // [0,256)   per-expert token count
#define M_FILL(e) (256 + (e) * 32)    // [256,512) atomic fill cursor
#define M_OFF  512                    // [8] padded row base per expert
#define M_NMT  520                    // [1] number of m-tiles
#define M_TE   528                    // [72] m-tile -> expert
#define M_TB   600                    // [72] m-tile -> global row base
#define M_TICKET 704                  // [1] gate last-block ticket
#define M_INTS 1024

typedef unsigned short u16;
typedef __attribute__((ext_vector_type(8))) short bf16x8;  // 8 bf16 in 4 VGPRs
typedef __attribute__((ext_vector_type(4))) float f32x4;

// workspace offsets (bytes)
// xb [0,16M) and wupb [16M,48M) are dead after k_up; slot [T][2][D] bf16 (33.5M)
// overlaps them (k_down/k_combine run strictly after k_up on the stream).
#define OFF_XB   ((size_t)0)                                     // [T][D] bf16  16 MB
#define OFF_WUPB (OFF_XB + (size_t)T_NUM * D_DIM * 2)            // [E][HE][D] bf16 32 MB
#define OFF_SLOT ((size_t)0)                                     // [T][2][D] bf16 33.5 MB (overlap)
#define OFF_WDNB (OFF_WUPB + (size_t)E_NUM * HE_DIM * D_DIM * 2) // [E][D][HE] bf16 32 MB
#define OFF_H    (OFF_WDNB + (size_t)E_NUM * D_DIM * HE_DIM * 2) // [MAXROWS][HE] bf16 18.9 MB
#define OFF_SCR  (OFF_H + (size_t)MAXROWS * HE_DIM * 2)          // [TK] f32 slot score
#define OFF_EIDX (OFF_SCR + (size_t)TK_NUM * 4)                  // [TK] int slot expert
#define OFF_RT   (OFF_EIDX + (size_t)TK_NUM * 4)                 // [MAXROWS] int row->slot id
#define OFF_RS   (OFF_RT + (size_t)MAXROWS * 4)                  // [MAXROWS] f32 row score
#define OFF_META (OFF_RS + (size_t)MAXROWS * 4)                  // ints

__device__ __forceinline__ u16 f2bf(float f) {
  unsigned u = __float_as_uint(f);
  u += 0x7FFFu + ((u >> 16) & 1u);   // round-to-nearest-even
  return (u16)(u >> 16);
}
__device__ __forceinline__ float bf_lo(unsigned u) { return __uint_as_float(u << 16); }
__device__ __forceinline__ float bf_hi(unsigned u) { return __uint_as_float(u & 0xFFFF0000u); }

__device__ __forceinline__ void gload16(const void* g, void* l) {
  // async global->LDS, 16B per lane; LDS dest = wave-uniform base + lane*16
  __builtin_amdgcn_global_load_lds((const __attribute__((address_space(1))) void*)g,
                                   (__attribute__((address_space(3))) void*)l,
                                   16, 0, 0);
}

// counted waits (T4): never drain vmcnt to 0 in the steady-state loop.
#define WAIT_VM4 asm volatile("s_waitcnt vmcnt(4)" ::: "memory")
#define WAIT_VM0 asm volatile("s_waitcnt vmcnt(0)" ::: "memory")
#define SBAR     { __builtin_amdgcn_s_barrier(); asm volatile("" ::: "memory"); }

// ---------------- f32 -> bf16 weight conversion + meta/rows init (one launch) ----------------
__global__ void k_cvt2(const float4* __restrict__ s1, const float4* __restrict__ s2,
                       ushort4* __restrict__ d1, ushort4* __restrict__ d2, int n4,
                       int* __restrict__ meta, int* __restrict__ rows_slot,
                       float* __restrict__ rowscore) {
  const int i0 = blockIdx.x * blockDim.x + threadIdx.x;
  if (i0 < M_INTS) meta[i0] = 0;
  if (i0 < MAXROWS) { rows_slot[i0] = -1; rowscore[i0] = 0.0f; }
  const int st = gridDim.x * blockDim.x;
  for (int i = i0; i < 2 * n4; i += st) {
    const float4* s = (i < n4) ? s1 : s2;
    ushort4* d = (i < n4) ? d1 : d2;
    int j = (i < n4) ? i : i - n4;
    float4 v = s[j];
    ushort4 o;
    o.x = f2bf(v.x); o.y = f2bf(v.y); o.z = f2bf(v.z); o.w = f2bf(v.w);
    d[j] = o;
  }
}

// ---------------- gate: Wg1 in LDS, LDS count histogram, padded global atomics ----------------
// Last block to finish (device ticket) also computes the offsets + tile map.
__global__ __launch_bounds__(256) void k_gate(
    const float4* __restrict__ x4, const float4* __restrict__ Wg1_4,
    const float* __restrict__ Wg2, ushort4* __restrict__ xb4,
    int* __restrict__ eidx, float* __restrict__ scr, int* __restrict__ meta) {
  __shared__ float4 wg1s[E_NUM * (D_DIM / 4)];   // 8*512*16B = 64 KB
  __shared__ int cnt_s[E_NUM];
  __shared__ int lastf;
  const int tid = threadIdx.x;
  if (tid < E_NUM) cnt_s[tid] = 0;
#pragma unroll
  for (int i = 0; i < 16; ++i) wg1s[tid + i * 256] = Wg1_4[tid + i * 256];
  __syncthreads();

  const int w = tid >> 6;
  const int lane = tid & 63;
  for (int j = 0; j < 4; ++j) {
    const int t = blockIdx.x * 16 + w * 4 + j;
    float acc[E_NUM];
#pragma unroll
    for (int e = 0; e < E_NUM; ++e) acc[e] = 0.f;
#pragma unroll
    for (int i = 0; i < 8; ++i) {
      const int c = lane + i * 64;                 // float4 index within row (0..511)
      float4 xv = x4[(size_t)t * 512 + c];
      ushort4 o;
      o.x = f2bf(xv.x); o.y = f2bf(xv.y); o.z = f2bf(xv.z); o.w = f2bf(xv.w);
      xb4[(size_t)t * 512 + c] = o;
#pragma unroll
      for (int e = 0; e < E_NUM; ++e) {
        float4 wv = wg1s[e * 512 + c];
        acc[e] += xv.x * wv.x + xv.y * wv.y + xv.z * wv.z + xv.w * wv.w;
      }
    }
#pragma unroll
    for (int e = 0; e < E_NUM; ++e) {
      float v = acc[e];
#pragma unroll
      for (int off = 32; off; off >>= 1) v += __shfl_xor(v, off, 64);
      acc[e] = v;
    }
    if (lane == 0) {
      float l1[E_NUM], lg[E_NUM];
#pragma unroll
      for (int e = 0; e < E_NUM; ++e) l1[e] = tanhf(acc[e]);
#pragma unroll
      for (int i = 0; i < E_NUM; ++i) {
        float s = 0.f;
#pragma unroll
        for (int e = 0; e < E_NUM; ++e) s += l1[e] * Wg2[i * E_NUM + e];
        lg[i] = s;
      }
      // stable top-2 (lowest index wins ties, like jax.lax.top_k)
      int i0 = 0; float v0 = lg[0];
#pragma unroll
      for (int i = 1; i < E_NUM; ++i) if (lg[i] > v0) { v0 = lg[i]; i0 = i; }
      int i1 = -1; float v1 = -3.4e38f;
#pragma unroll
      for (int i = 0; i < E_NUM; ++i) if (i != i0 && lg[i] > v1) { v1 = lg[i]; i1 = i; }
      float e1 = __expf(v1 - v0);
      float s0 = 1.f / (1.f + e1);
      float s1 = e1 * s0;
      eidx[t * 2] = i0; eidx[t * 2 + 1] = i1;
      scr[t * 2] = s0;  scr[t * 2 + 1] = s1;
      atomicAdd(&cnt_s[i0], 1);      // LDS atomic — block-local, cheap
      atomicAdd(&cnt_s[i1], 1);
    }
  }
  __syncthreads();
  if (tid < E_NUM) atomicAdd(&meta[M_CNT(tid)], cnt_s[tid]);  // 8/block, padded lines

  // ---- last-block-done: compute offsets + tile map ----
  if (tid == 0) {
    __threadfence();
    lastf = (atomicAdd(&meta[M_TICKET], 1) == (int)gridDim.x - 1);
  }
  __syncthreads();
  if (lastf && tid < 64) {
    const int l2 = tid;
    int cnt = (l2 < E_NUM) ? atomicAdd(&meta[M_CNT(l2)], 0) : 0;
    int tiles = (cnt + TILE - 1) / TILE;
    int pre = tiles;
#pragma unroll
    for (int off = 1; off < E_NUM; off <<= 1) {
      int v = __shfl_up(pre, off, 64);
      if (l2 >= off && l2 < E_NUM) pre += v;
    }
    int tb_excl = pre - tiles;               // exclusive prefix (valid lanes 0..7)
    if (l2 < E_NUM) meta[M_OFF + l2] = tb_excl * TILE;
    const int nmt = __shfl(pre, E_NUM - 1, 64);
    if (l2 == 0) meta[M_NMT] = nmt;
    int tb[E_NUM];
#pragma unroll
    for (int k = 0; k < E_NUM; ++k) tb[k] = __shfl(tb_excl, k, 64);
    for (int mt = l2; mt < nmt; mt += 64) {
      int e = 0;
#pragma unroll
      for (int k = 1; k < E_NUM; ++k) if (mt >= tb[k]) e = k;
      meta[M_TE + mt] = e;
      meta[M_TB + mt] = mt * TILE;           // tile bases are contiguous multiples of TILE
    }
  }
}

// ---------------- compaction: wave-aggregated fetch-add ----------------
__global__ void k_assign(const int* __restrict__ eidx, const float* __restrict__ scr,
                         int* __restrict__ meta, int* __restrict__ rows_slot,
                         float* __restrict__ rowscore) {
  int i = blockIdx.x * blockDim.x + threadIdx.x;
  const int lane = threadIdx.x & 63;
  int e = eidx[i];
  int pos = 0;
#pragma unroll
  for (int ex = 0; ex < E_NUM; ++ex) {
    unsigned long long m = __ballot(e == ex);
    if (e == ex) {
      int leader = __ffsll((long long)m) - 1;
      int rank = __popcll(m & ((1ull << lane) - 1ull));
      int b = 0;
      if (lane == leader) b = atomicAdd(&meta[M_FILL(ex)], __popcll(m));
      b = __shfl(b, leader, 64);
      pos = b + rank;
    }
  }
  int r = meta[M_OFF + e] + pos;
  rows_slot[r] = i;            // slot id (token = i>>1)
  rowscore[r] = scr[i];
}

// ---------------- grouped up-GEMM: h = silu(Xg @ Wup[e]^T + bup[e]) ----------------
// BK=32 x 3 LDS buffers = 48 KB -> 3 blocks/CU co-resident (the r1-vs-r3 A/B
// showed co-residency is the dominant latency hider) PLUS counted vmcnt(4):
// tile t+2's loads stay in flight across the barrier; vmcnt never drains to 0
// in steady state. 256 threads, 4 waves of 64x64 (4x4 frags, ds_read:MFMA=0.5).
// Swizzle: staged chunk pos = c ^ ((row>>2)&3) -> 2 lanes/bank-group (free).
__global__ __launch_bounds__(256) void k_up(
    const u16* __restrict__ xb, const u16* __restrict__ wupb,
    const float* __restrict__ bup, const int* __restrict__ meta,
    const int* __restrict__ rows_slot, u16* __restrict__ hbuf) {
  const int mt = blockIdx.y;
  if (mt >= meta[M_NMT]) return;
  const int e = meta[M_TE + mt];
  const int mbase = meta[M_TB + mt];
  const int nt = blockIdx.x;

  __shared__ u16 As[3][TILE * BK];   // 3 x 8 KB
  __shared__ u16 Bs[3][TILE * BK];   // 3 x 8 KB

  const int tid = threadIdx.x;
  const int lane = tid & 63;
  const int w = tid >> 6;                                // 0..3
  const int r0 = tid >> 2;                               // staged row 0..63
  const int cb = (((tid & 3) ^ ((r0 >> 2) & 3)) * 8);    // swizzled 16B chunk (u16 units)

  const u16* gA[2];
  const u16* gB[2];
#pragma unroll
  for (int j = 0; j < 2; ++j) {
    int s = rows_slot[mbase + r0 + 64 * j]; if (s < 0) s = 0;
    gA[j] = xb + (size_t)(s >> 1) * D_DIM + cb;
    gB[j] = wupb + ((size_t)e * HE_DIM + nt * TILE + r0 + 64 * j) * D_DIM + cb;
  }

  const int wm = (w & 1) * 64;
  const int wn = (w >> 1) * 64;
  const int quad = lane >> 4;
  const int l16 = lane & 15;
  const int koff = ((quad ^ (l16 >> 2)) & 3) * 8;        // read-side swizzle (u16)

  f32x4 acc[4][4] = {};

#define STAGE_UP(buf, k0) \
  { gload16(gA[0] + (k0), &As[buf][tid * 8]);        \
    gload16(gA[1] + (k0), &As[buf][tid * 8 + 2048]); \
    gload16(gB[0] + (k0), &Bs[buf][tid * 8]);        \
    gload16(gB[1] + (k0), &Bs[buf][tid * 8 + 2048]); }

  STAGE_UP(0, 0);
  STAGE_UP(1, BK);
  WAIT_VM4;                             // tile 0 resident (tile 1 may be in flight)
  SBAR;
  int cur = 0;
  const int NT = D_DIM / BK;            // 64
  for (int t = 0; t < NT; ++t) {
    const bool pf = (t + 2 < NT);
    const int nxt = (cur == 0) ? 2 : cur - 1;  // (cur+2)%3
    if (pf) STAGE_UP(nxt, (t + 2) * BK);
    const u16* pa0 = &As[cur][(wm + l16) * BK + koff];
    const u16* pb0 = &Bs[cur][(wn + l16) * BK + koff];
    bf16x8 af[4], bfr[4];
#pragma unroll
    for (int i = 0; i < 4; ++i) {
      af[i]  = *(const bf16x8*)(pa0 + i * 16 * BK);
      bfr[i] = *(const bf16x8*)(pb0 + i * 16 * BK);
    }
    __builtin_amdgcn_s_setprio(1);
#pragma unroll
    for (int mi = 0; mi < 4; ++mi)
#pragma unroll
      for (int ni = 0; ni < 4; ++ni)
        acc[mi][ni] = __builtin_amdgcn_mfma_f32_16x16x32_bf16(af[mi], bfr[ni], acc[mi][ni], 0, 0, 0);
    __builtin_amdgcn_s_setprio(0);
    if (pf) { WAIT_VM4; } else { WAIT_VM0; }   // t+1 resident; t+2 stays in flight
    SBAR;
    cur = (cur == 2) ? 0 : cur + 1;
  }

#pragma unroll
  for (int mi = 0; mi < 4; ++mi) {
    const int m = wm + mi * 16 + quad * 4;
#pragma unroll
    for (int ni = 0; ni < 4; ++ni) {
      const int ng = nt * TILE + wn + ni * 16 + l16;
      const float bias = bup[e * HE_DIM + ng];
#pragma unroll
      for (int r = 0; r < 4; ++r) {
        float v = acc[mi][ni][r] + bias;
        v = v / (1.0f + __expf(-v));     // silu
        hbuf[(size_t)(mbase + m + r) * HE_DIM + ng] = f2bf(v);
      }
    }
  }
}

// ---------------- grouped down-GEMM: slot[s] = score * (h @ Wdown[e]^T + bdown[e]) ----------------
__global__ __launch_bounds__(256) void k_down(
    const u16* __restrict__ hbuf, const u16* __restrict__ wdnb,
    const float* __restrict__ bdown, const int* __restrict__ meta,
    const int* __restrict__ rows_slot, const float* __restrict__ rowscore,
    u16* __restrict__ slot) {
  const int mt = blockIdx.y;
  if (mt >= meta[M_NMT]) return;
  const int e = meta[M_TE + mt];
  const int mbase = meta[M_TB + mt];
  const int nt = blockIdx.x;

  __shared__ u16 As[3][TILE * BK];
  __shared__ u16 Bs[3][TILE * BK];

  const int tid = threadIdx.x;
  const int lane = tid & 63;
  const int w = tid >> 6;
  const int r0 = tid >> 2;
  const int cb = (((tid & 3) ^ ((r0 >> 2) & 3)) * 8);

  const u16* gA[2];
  const u16* gB[2];
#pragma unroll
  for (int j = 0; j < 2; ++j) {
    gA[j] = hbuf + (size_t)(mbase + r0 + 64 * j) * HE_DIM + cb;
    gB[j] = wdnb + ((size_t)e * D_DIM + nt * TILE + r0 + 64 * j) * HE_DIM + cb;
  }

  const int wm = (w & 1) * 64;
  const int wn = (w >> 1) * 64;
  const int quad = lane >> 4;
  const int l16 = lane & 15;
  const int koff = ((quad ^ (l16 >> 2)) & 3) * 8;

  f32x4 acc[4][4] = {};

#define STAGE_DN(buf, k0) \
  { gload16(gA[0] + (k0), &As[buf][tid * 8]);        \
    gload16(gA[1] + (k0), &As[buf][tid * 8 + 2048]); \
    gload16(gB[0] + (k0), &Bs[buf][tid * 8]);        \
    gload16(gB[1] + (k0), &Bs[buf][tid * 8 + 2048]); }

  STAGE_DN(0, 0);
  STAGE_DN(1, BK);
  WAIT_VM4;
  SBAR;
  int cur = 0;
  const int NT = HE_DIM / BK;           // 32
  for (int t = 0; t < NT; ++t) {
    const bool pf = (t + 2 < NT);
    const int nxt = (cur == 0) ? 2 : cur - 1;
    if (pf) STAGE_DN(nxt, (t + 2) * BK);
    const u16* pa0 = &As[cur][(wm + l16) * BK + koff];
    const u16* pb0 = &Bs[cur][(wn + l16) * BK + koff];
    bf16x8 af[4], bfr[4];
#pragma unroll
    for (int i = 0; i < 4; ++i) {
      af[i]  = *(const bf16x8*)(pa0 + i * 16 * BK);
      bfr[i] = *(const bf16x8*)(pb0 + i * 16 * BK);
    }
    __builtin_amdgcn_s_setprio(1);
#pragma unroll
    for (int mi = 0; mi < 4; ++mi)
#pragma unroll
      for (int ni = 0; ni < 4; ++ni)
        acc[mi][ni] = __builtin_amdgcn_mfma_f32_16x16x32_bf16(af[mi], bfr[ni], acc[mi][ni], 0, 0, 0);
    __builtin_amdgcn_s_setprio(0);
    if (pf) { WAIT_VM4; } else { WAIT_VM0; }
    SBAR;
    cur = (cur == 2) ? 0 : cur + 1;
  }

#pragma unroll
  for (int mi = 0; mi < 4; ++mi) {
    const int m = wm + mi * 16 + quad * 4;
#pragma unroll
    for (int r = 0; r < 4; ++r) {
      const int rg = mbase + m + r;
      const int s = rows_slot[rg];
      const float sc = rowscore[rg];
      if (s < 0) continue;               // padding row
      u16* dst = slot + (size_t)s * D_DIM;
#pragma unroll
      for (int ni = 0; ni < 4; ++ni) {
        const int ng = nt * TILE + wn + ni * 16 + l16;
        float v = (acc[mi][ni][r] + bdown[e * D_DIM + ng]) * sc;
        dst[ng] = f2bf(v);
      }
    }
  }
}

// ---------------- combine: out[t] = slot[t][0] + slot[t][1] (fully coalesced) ----------------
__global__ __launch_bounds__(256) void k_combine(const u16* __restrict__ slot,
                                                 float* __restrict__ out) {
  int i = blockIdx.x * blockDim.x + threadIdx.x;   // one 16B chunk (8 bf16) per thread
  int t = i >> 8;                                  // D/8 = 256 chunks per token
  int c = i & 255;
  const uint4* p0 = (const uint4*)(slot + (size_t)(t * 2) * D_DIM) + c;
  const uint4* p1 = (const uint4*)(slot + (size_t)(t * 2 + 1) * D_DIM) + c;
  uint4 a = *p0, b = *p1;
  float4 o0, o1;
  o0.x = bf_lo(a.x) + bf_lo(b.x);  o0.y = bf_hi(a.x) + bf_hi(b.x);
  o0.z = bf_lo(a.y) + bf_lo(b.y);  o0.w = bf_hi(a.y) + bf_hi(b.y);
  o1.x = bf_lo(a.z) + bf_lo(b.z);  o1.y = bf_hi(a.z) + bf_hi(b.z);
  o1.z = bf_lo(a.w) + bf_lo(b.w);  o1.w = bf_hi(a.w) + bf_hi(b.w);
  float4* po = (float4*)(out + (size_t)t * D_DIM) + c * 2;
  po[0] = o0;
  po[1] = o1;
}

// ---------------- launcher ----------------
extern "C" void kernel_launch(void* const* d_in, const int* in_sizes, int n_in,
                              void* d_out, int out_size, void* d_ws, size_t ws_size,
                              hipStream_t stream) {
  const float* x     = (const float*)d_in[0];
  const float* Wg1   = (const float*)d_in[1];
  const float* Wg2   = (const float*)d_in[2];
  const float* Wup   = (const float*)d_in[3];
  const float* bup   = (const float*)d_in[4];
  const float* Wdown = (const float*)d_in[5];
  const float* bdown = (const float*)d_in[6];
  float* out = (float*)d_out;

  char* ws = (char*)d_ws;
  u16*   xb         = (u16*)(ws + OFF_XB);
  u16*   wupb       = (u16*)(ws + OFF_WUPB);
  u16*   wdnb       = (u16*)(ws + OFF_WDNB);
  u16*   hbuf       = (u16*)(ws + OFF_H);
  u16*   slotbuf    = (u16*)(ws + OFF_SLOT);
  float* scr        = (float*)(ws + OFF_SCR);
  int*   eidx       = (int*)(ws + OFF_EIDX);
  int*   rows_slot  = (int*)(ws + OFF_RT);
  float* rowscore   = (float*)(ws + OFF_RS);
  int*   meta       = (int*)(ws + OFF_META);

  k_cvt2<<<8192, 256, 0, stream>>>((const float4*)Wup, (const float4*)Wdown,
                                   (ushort4*)wupb, (ushort4*)wdnb,
                                   E_NUM * HE_DIM * D_DIM / 4,
                                   meta, rows_slot, rowscore);
  k_gate<<<T_NUM / 16, 256, 0, stream>>>((const float4*)x, (const float4*)Wg1, Wg2,
                                         (ushort4*)xb, eidx, scr, meta);
  k_assign<<<TK_NUM / 256, 256, 0, stream>>>(eidx, scr, meta, rows_slot, rowscore);
  k_up<<<dim3(HE_DIM / TILE, MAXMT), 256, 0, stream>>>(xb, wupb, bup, meta, rows_slot, hbuf);
  k_down<<<dim3(D_DIM / TILE, MAXMT), 256, 0, stream>>>(hbuf, wdnb, bdown, meta,
                                                        rows_slot, rowscore, slotbuf);
  k_combine<<<T_NUM * D_DIM / 8 / 256, 256, 0, stream>>>(slotbuf, out);
}

// Round 6
// 392.549 us; speedup vs baseline: 1.0717x; 1.0269x over previous
//
#include <hip/hip_runtime.h>
#include <hip/hip_bf16.h>

// ---------------- problem constants ----------------
#define D_DIM 2048
#define HE_DIM 1024
#define E_NUM 8
#define T_NUM 4096
#define TK_NUM 8192           // T * K (top-2)
#define TILE 128              // GEMM M/N tile
#define BK 64                 // GEMM K tile (proven conflict-free swizzle)
#define MAXROWS 9216          // TK + E*TILE padding
#define MAXMT 72              // max M-tiles: 64 + 8

// meta (int) layout in workspace — counters padded to 128 B (32 ints).
#define M_CNT(e)  ((e) * 32)          // [0,256)   per-expert token count
#define M_FILL(e) (256 + (e) * 32)    // [256,512) atomic fill cursor
#define M_OFF  512                    // [8] padded row base per expert
#define M_NMT  520                    // [1] number of m-tiles
#define M_TE   528                    // [72] m-tile -> expert
#define M_TB   600                    // [72] m-tile -> global row base
#define M_TICKET 704                  // [1] gate last-block ticket
#define M_INTS 1024

typedef unsigned short u16;
typedef __attribute__((ext_vector_type(8))) short bf16x8;  // 8 bf16 in 4 VGPRs
typedef __attribute__((ext_vector_type(4))) float f32x4;

// workspace offsets (bytes). Weights are now read as f32 directly from the
// input tensors (no cvt pass), so the workspace only holds xb/hbuf/slot/meta.
// xb [0,16M) is dead after k_up; slot [T][2][D] bf16 (32 MiB) overlaps it
// (k_down/k_combine run strictly after k_up on the stream).
#define OFF_XB   ((size_t)0)                                     // [T][D] bf16  16 MB
#define OFF_SLOT ((size_t)0)                                     // [T][2][D] bf16 32 MiB (overlap)
#define OFF_H    ((size_t)33554432)                              // [MAXROWS][HE] bf16 18.9 MB
#define OFF_SCR  (OFF_H + (size_t)MAXROWS * HE_DIM * 2)          // [TK] f32 slot score
#define OFF_EIDX (OFF_SCR + (size_t)TK_NUM * 4)                  // [TK] int slot expert
#define OFF_RT   (OFF_EIDX + (size_t)TK_NUM * 4)                 // [MAXROWS] int row->slot id
#define OFF_RS   (OFF_RT + (size_t)MAXROWS * 4)                  // [MAXROWS] f32 row score
#define OFF_META (OFF_RS + (size_t)MAXROWS * 4)                  // ints

__device__ __forceinline__ u16 f2bf(float f) {
  unsigned u = __float_as_uint(f);
  u += 0x7FFFu + ((u >> 16) & 1u);   // round-to-nearest-even
  return (u16)(u >> 16);
}
__device__ __forceinline__ float bf_lo(unsigned u) { return __uint_as_float(u << 16); }
__device__ __forceinline__ float bf_hi(unsigned u) { return __uint_as_float(u & 0xFFFF0000u); }

__device__ __forceinline__ void gload16(const void* g, void* l) {
  // async global->LDS, 16B per lane; LDS dest = wave-uniform base + lane*16
  __builtin_amdgcn_global_load_lds((const __attribute__((address_space(1))) void*)g,
                                   (__attribute__((address_space(3))) void*)l,
                                   16, 0, 0);
}

// ---------------- init: meta zero, rows poisoned to "padding" ----------------
__global__ void k_init(int* __restrict__ meta, int* __restrict__ rows_slot,
                       float* __restrict__ rowscore) {
  int i = blockIdx.x * blockDim.x + threadIdx.x;
  if (i < M_INTS) meta[i] = 0;
  if (i < MAXROWS) { rows_slot[i] = -1; rowscore[i] = 0.0f; }
}

// ---------------- gate: Wg1 in LDS, LDS count histogram, padded global atomics ----------------
// Last block to finish (device ticket) also computes the offsets + tile map.
__global__ __launch_bounds__(256) void k_gate(
    const float4* __restrict__ x4, const float4* __restrict__ Wg1_4,
    const float* __restrict__ Wg2, ushort4* __restrict__ xb4,
    int* __restrict__ eidx, float* __restrict__ scr, int* __restrict__ meta) {
  __shared__ float4 wg1s[E_NUM * (D_DIM / 4)];   // 8*512*16B = 64 KB
  __shared__ int cnt_s[E_NUM];
  __shared__ int lastf;
  const int tid = threadIdx.x;
  if (tid < E_NUM) cnt_s[tid] = 0;
#pragma unroll
  for (int i = 0; i < 16; ++i) wg1s[tid + i * 256] = Wg1_4[tid + i * 256];
  __syncthreads();

  const int w = tid >> 6;
  const int lane = tid & 63;
  for (int j = 0; j < 4; ++j) {
    const int t = blockIdx.x * 16 + w * 4 + j;
    float acc[E_NUM];
#pragma unroll
    for (int e = 0; e < E_NUM; ++e) acc[e] = 0.f;
#pragma unroll
    for (int i = 0; i < 8; ++i) {
      const int c = lane + i * 64;                 // float4 index within row (0..511)
      float4 xv = x4[(size_t)t * 512 + c];
      ushort4 o;
      o.x = f2bf(xv.x); o.y = f2bf(xv.y); o.z = f2bf(xv.z); o.w = f2bf(xv.w);
      xb4[(size_t)t * 512 + c] = o;
#pragma unroll
      for (int e = 0; e < E_NUM; ++e) {
        float4 wv = wg1s[e * 512 + c];
        acc[e] += xv.x * wv.x + xv.y * wv.y + xv.z * wv.z + xv.w * wv.w;
      }
    }
#pragma unroll
    for (int e = 0; e < E_NUM; ++e) {
      float v = acc[e];
#pragma unroll
      for (int off = 32; off; off >>= 1) v += __shfl_xor(v, off, 64);
      acc[e] = v;
    }
    if (lane == 0) {
      float l1[E_NUM], lg[E_NUM];
#pragma unroll
      for (int e = 0; e < E_NUM; ++e) l1[e] = tanhf(acc[e]);
#pragma unroll
      for (int i = 0; i < E_NUM; ++i) {
        float s = 0.f;
#pragma unroll
        for (int e = 0; e < E_NUM; ++e) s += l1[e] * Wg2[i * E_NUM + e];
        lg[i] = s;
      }
      // stable top-2 (lowest index wins ties, like jax.lax.top_k)
      int i0 = 0; float v0 = lg[0];
#pragma unroll
      for (int i = 1; i < E_NUM; ++i) if (lg[i] > v0) { v0 = lg[i]; i0 = i; }
      int i1 = -1; float v1 = -3.4e38f;
#pragma unroll
      for (int i = 0; i < E_NUM; ++i) if (i != i0 && lg[i] > v1) { v1 = lg[i]; i1 = i; }
      float e1 = __expf(v1 - v0);
      float s0 = 1.f / (1.f + e1);
      float s1 = e1 * s0;
      eidx[t * 2] = i0; eidx[t * 2 + 1] = i1;
      scr[t * 2] = s0;  scr[t * 2 + 1] = s1;
      atomicAdd(&cnt_s[i0], 1);      // LDS atomic — block-local, cheap
      atomicAdd(&cnt_s[i1], 1);
    }
  }
  __syncthreads();
  if (tid < E_NUM) atomicAdd(&meta[M_CNT(tid)], cnt_s[tid]);  // 8/block, padded lines

  // ---- last-block-done: compute offsets + tile map ----
  if (tid == 0) {
    __threadfence();
    lastf = (atomicAdd(&meta[M_TICKET], 1) == (int)gridDim.x - 1);
  }
  __syncthreads();
  if (lastf && tid < 64) {
    const int l2 = tid;
    int cnt = (l2 < E_NUM) ? atomicAdd(&meta[M_CNT(l2)], 0) : 0;
    int tiles = (cnt + TILE - 1) / TILE;
    int pre = tiles;
#pragma unroll
    for (int off = 1; off < E_NUM; off <<= 1) {
      int v = __shfl_up(pre, off, 64);
      if (l2 >= off && l2 < E_NUM) pre += v;
    }
    int tb_excl = pre - tiles;               // exclusive prefix (valid lanes 0..7)
    if (l2 < E_NUM) meta[M_OFF + l2] = tb_excl * TILE;
    const int nmt = __shfl(pre, E_NUM - 1, 64);
    if (l2 == 0) meta[M_NMT] = nmt;
    int tb[E_NUM];
#pragma unroll
    for (int k = 0; k < E_NUM; ++k) tb[k] = __shfl(tb_excl, k, 64);
    for (int mt = l2; mt < nmt; mt += 64) {
      int e = 0;
#pragma unroll
      for (int k = 1; k < E_NUM; ++k) if (mt >= tb[k]) e = k;
      meta[M_TE + mt] = e;
      meta[M_TB + mt] = mt * TILE;           // tile bases are contiguous multiples of TILE
    }
  }
}

// ---------------- compaction: wave-aggregated fetch-add ----------------
__global__ void k_assign(const int* __restrict__ eidx, const float* __restrict__ scr,
                         int* __restrict__ meta, int* __restrict__ rows_slot,
                         float* __restrict__ rowscore) {
  int i = blockIdx.x * blockDim.x + threadIdx.x;
  const int lane = threadIdx.x & 63;
  int e = eidx[i];
  int pos = 0;
#pragma unroll
  for (int ex = 0; ex < E_NUM; ++ex) {
    unsigned long long m = __ballot(e == ex);
    if (e == ex) {
      int leader = __ffsll((long long)m) - 1;
      int rank = __popcll(m & ((1ull << lane) - 1ull));
      int b = 0;
      if (lane == leader) b = atomicAdd(&meta[M_FILL(ex)], __popcll(m));
      b = __shfl(b, leader, 64);
      pos = b + rank;
    }
  }
  int r = meta[M_OFF + e] + pos;
  rows_slot[r] = i;            // slot id (token = i>>1)
  rowscore[r] = scr[i];
}

// ---------------- grouped up-GEMM: h = silu(Xg @ Wup[e]^T + bup[e]) ----------------
// r1 structure (proven 75 µs, 0 bank conflicts) with the weight-conversion
// pass eliminated: B is read as f32 DIRECTLY from Wup and converted to bf16
// during staging. T14 split: f32 loads issue BEFORE the compute phase (latency
// hides under MFMA), cvt + ds_write after it. A (xb, bf16) keeps
// global_load_lds. Saves the standalone 384 MB cvt kernel (~60 us).
__global__ __launch_bounds__(512) void k_up(
    const u16* __restrict__ xb, const float* __restrict__ Wup,
    const float* __restrict__ bup, const int* __restrict__ meta,
    const int* __restrict__ rows_slot, u16* __restrict__ hbuf) {
  const int mt = blockIdx.y;
  if (mt >= meta[M_NMT]) return;
  const int e = meta[M_TE + mt];
  const int mbase = meta[M_TB + mt];
  const int nt = blockIdx.x;

  __shared__ u16 As[2][TILE * BK];   // 2 x 16 KB
  __shared__ u16 Bs[2][TILE * BK];   // 2 x 16 KB

  const int tid = threadIdx.x;
  const int lane = tid & 63;
  const int w = tid >> 6;                                // 0..7
  const int r0 = tid >> 3;                               // staged row 0..63
  const int cb = (((tid & 7) ^ (r0 & 7)) * 8);           // swizzled k-chunk (elements)

  const u16* gA[2];
  const float* gB[2];
#pragma unroll
  for (int j = 0; j < 2; ++j) {
    int s = rows_slot[mbase + r0 + 64 * j]; if (s < 0) s = 0;
    gA[j] = xb + (size_t)(s >> 1) * D_DIM + cb;
    gB[j] = Wup + ((size_t)e * HE_DIM + nt * TILE + r0 + 64 * j) * D_DIM + cb;
  }

  const int wm = (w & 1) * 64;
  const int wn = (w >> 1) * 32;
  const int quad = lane >> 4;
  const int l16 = lane & 15;
  const int sw = l16 & 7;

  f32x4 acc[4][2] = {};
  float4 br[2][2];                   // in-flight f32 B fragments (static idx)

#define A_STAGE_UP(buf, k0) \
  { gload16(gA[0] + (k0), &As[buf][tid * 8]); \
    gload16(gA[1] + (k0), &As[buf][tid * 8 + 4096]); }
#define B_LOAD_UP(k0) \
  { br[0][0] = *(const float4*)(gB[0] + (k0)); \
    br[0][1] = *(const float4*)(gB[0] + (k0) + 4); \
    br[1][0] = *(const float4*)(gB[1] + (k0)); \
    br[1][1] = *(const float4*)(gB[1] + (k0) + 4); }
#define B_WRITE_UP(buf) \
  { _Pragma("unroll") \
    for (int j = 0; j < 2; ++j) { \
      bf16x8 v; \
      v[0] = (short)f2bf(br[j][0].x); v[1] = (short)f2bf(br[j][0].y); \
      v[2] = (short)f2bf(br[j][0].z); v[3] = (short)f2bf(br[j][0].w); \
      v[4] = (short)f2bf(br[j][1].x); v[5] = (short)f2bf(br[j][1].y); \
      v[6] = (short)f2bf(br[j][1].z); v[7] = (short)f2bf(br[j][1].w); \
      *(bf16x8*)(&Bs[buf][tid * 8 + 4096 * j]) = v; } }

  B_LOAD_UP(0);
  A_STAGE_UP(0, 0);
  B_WRITE_UP(0);
  __syncthreads();                      // tile 0 resident
  int cur = 0;
  for (int k0 = 0; k0 < D_DIM; k0 += BK) {
    const bool pf = (k0 + BK < D_DIM);
    if (pf) { B_LOAD_UP(k0 + BK); A_STAGE_UP(cur ^ 1, k0 + BK); }  // issue early
    const u16* pa0 = &As[cur][(wm + l16) * BK];
    const u16* pb0 = &Bs[cur][(wn + l16) * BK];
#pragma unroll
    for (int h = 0; h < 2; ++h) {
      const int off = ((h * 4 + quad) ^ sw) * 8;
      bf16x8 af[4], bfr[2];
#pragma unroll
      for (int i = 0; i < 4; ++i) af[i] = *(const bf16x8*)(pa0 + i * 16 * BK + off);
#pragma unroll
      for (int i = 0; i < 2; ++i) bfr[i] = *(const bf16x8*)(pb0 + i * 16 * BK + off);
#pragma unroll
      for (int mi = 0; mi < 4; ++mi)
#pragma unroll
        for (int ni = 0; ni < 2; ++ni)
          acc[mi][ni] = __builtin_amdgcn_mfma_f32_16x16x32_bf16(af[mi], bfr[ni], acc[mi][ni], 0, 0, 0);
    }
    if (pf) B_WRITE_UP(cur ^ 1);        // write late: f32 latency hid under MFMA
    __syncthreads();                    // drains A-gloads + B ds_writes
    cur ^= 1;
  }

#pragma unroll
  for (int mi = 0; mi < 4; ++mi) {
    const int m = wm + mi * 16 + quad * 4;
#pragma unroll
    for (int ni = 0; ni < 2; ++ni) {
      const int ng = nt * TILE + wn + ni * 16 + l16;
      const float bias = bup[e * HE_DIM + ng];
#pragma unroll
      for (int r = 0; r < 4; ++r) {
        float v = acc[mi][ni][r] + bias;
        v = v / (1.0f + __expf(-v));     // silu
        hbuf[(size_t)(mbase + m + r) * HE_DIM + ng] = f2bf(v);
      }
    }
  }
}

// ---------------- grouped down-GEMM: slot[s] = score * (h @ Wdown[e]^T + bdown[e]) ----------------
__global__ __launch_bounds__(512) void k_down(
    const u16* __restrict__ hbuf, const float* __restrict__ Wdown,
    const float* __restrict__ bdown, const int* __restrict__ meta,
    const int* __restrict__ rows_slot, const float* __restrict__ rowscore,
    u16* __restrict__ slot) {
  const int mt = blockIdx.y;
  if (mt >= meta[M_NMT]) return;
  const int e = meta[M_TE + mt];
  const int mbase = meta[M_TB + mt];
  const int nt = blockIdx.x;

  __shared__ u16 As[2][TILE * BK];
  __shared__ u16 Bs[2][TILE * BK];

  const int tid = threadIdx.x;
  const int lane = tid & 63;
  const int w = tid >> 6;
  const int r0 = tid >> 3;
  const int cb = (((tid & 7) ^ (r0 & 7)) * 8);

  const u16* gA[2];
  const float* gB[2];
#pragma unroll
  for (int j = 0; j < 2; ++j) {
    gA[j] = hbuf + (size_t)(mbase + r0 + 64 * j) * HE_DIM + cb;
    gB[j] = Wdown + ((size_t)e * D_DIM + nt * TILE + r0 + 64 * j) * HE_DIM + cb;
  }

  const int wm = (w & 1) * 64;
  const int wn = (w >> 1) * 32;
  const int quad = lane >> 4;
  const int l16 = lane & 15;
  const int sw = l16 & 7;

  f32x4 acc[4][2] = {};
  float4 br[2][2];

#define A_STAGE_DN(buf, k0) \
  { gload16(gA[0] + (k0), &As[buf][tid * 8]); \
    gload16(gA[1] + (k0), &As[buf][tid * 8 + 4096]); }
#define B_LOAD_DN(k0) \
  { br[0][0] = *(const float4*)(gB[0] + (k0)); \
    br[0][1] = *(const float4*)(gB[0] + (k0) + 4); \
    br[1][0] = *(const float4*)(gB[1] + (k0)); \
    br[1][1] = *(const float4*)(gB[1] + (k0) + 4); }
#define B_WRITE_DN(buf) \
  { _Pragma("unroll") \
    for (int j = 0; j < 2; ++j) { \
      bf16x8 v; \
      v[0] = (short)f2bf(br[j][0].x); v[1] = (short)f2bf(br[j][0].y); \
      v[2] = (short)f2bf(br[j][0].z); v[3] = (short)f2bf(br[j][0].w); \
      v[4] = (short)f2bf(br[j][1].x); v[5] = (short)f2bf(br[j][1].y); \
      v[6] = (short)f2bf(br[j][1].z); v[7] = (short)f2bf(br[j][1].w); \
      *(bf16x8*)(&Bs[buf][tid * 8 + 4096 * j]) = v; } }

  B_LOAD_DN(0);
  A_STAGE_DN(0, 0);
  B_WRITE_DN(0);
  __syncthreads();
  int cur = 0;
  for (int k0 = 0; k0 < HE_DIM; k0 += BK) {
    const bool pf = (k0 + BK < HE_DIM);
    if (pf) { B_LOAD_DN(k0 + BK); A_STAGE_DN(cur ^ 1, k0 + BK); }
    const u16* pa0 = &As[cur][(wm + l16) * BK];
    const u16* pb0 = &Bs[cur][(wn + l16) * BK];
#pragma unroll
    for (int h = 0; h < 2; ++h) {
      const int off = ((h * 4 + quad) ^ sw) * 8;
      bf16x8 af[4], bfr[2];
#pragma unroll
      for (int i = 0; i < 4; ++i) af[i] = *(const bf16x8*)(pa0 + i * 16 * BK + off);
#pragma unroll
      for (int i = 0; i < 2; ++i) bfr[i] = *(const bf16x8*)(pb0 + i * 16 * BK + off);
#pragma unroll
      for (int mi = 0; mi < 4; ++mi)
#pragma unroll
        for (int ni = 0; ni < 2; ++ni)
          acc[mi][ni] = __builtin_amdgcn_mfma_f32_16x16x32_bf16(af[mi], bfr[ni], acc[mi][ni], 0, 0, 0);
    }
    if (pf) B_WRITE_DN(cur ^ 1);
    __syncthreads();
    cur ^= 1;
  }

#pragma unroll
  for (int mi = 0; mi < 4; ++mi) {
    const int m = wm + mi * 16 + quad * 4;
#pragma unroll
    for (int r = 0; r < 4; ++r) {
      const int rg = mbase + m + r;
      const int s = rows_slot[rg];
      const float sc = rowscore[rg];
      if (s < 0) continue;               // padding row
      u16* dst = slot + (size_t)s * D_DIM;
#pragma unroll
      for (int ni = 0; ni < 2; ++ni) {
        const int ng = nt * TILE + wn + ni * 16 + l16;
        float v = (acc[mi][ni][r] + bdown[e * D_DIM + ng]) * sc;
        dst[ng] = f2bf(v);
      }
    }
  }
}

// ---------------- combine: out[t] = slot[t][0] + slot[t][1] (fully coalesced) ----------------
__global__ __launch_bounds__(256) void k_combine(const u16* __restrict__ slot,
                                                 float* __restrict__ out) {
  int i = blockIdx.x * blockDim.x + threadIdx.x;   // one 16B chunk (8 bf16) per thread
  int t = i >> 8;                                  // D/8 = 256 chunks per token
  int c = i & 255;
  const uint4* p0 = (const uint4*)(slot + (size_t)(t * 2) * D_DIM) + c;
  const uint4* p1 = (const uint4*)(slot + (size_t)(t * 2 + 1) * D_DIM) + c;
  uint4 a = *p0, b = *p1;
  float4 o0, o1;
  o0.x = bf_lo(a.x) + bf_lo(b.x);  o0.y = bf_hi(a.x) + bf_hi(b.x);
  o0.z = bf_lo(a.y) + bf_lo(b.y);  o0.w = bf_hi(a.y) + bf_hi(b.y);
  o1.x = bf_lo(a.z) + bf_lo(b.z);  o1.y = bf_hi(a.z) + bf_hi(b.z);
  o1.z = bf_lo(a.w) + bf_lo(b.w);  o1.w = bf_hi(a.w) + bf_hi(b.w);
  float4* po = (float4*)(out + (size_t)t * D_DIM) + c * 2;
  po[0] = o0;
  po[1] = o1;
}

// ---------------- launcher ----------------
extern "C" void kernel_launch(void* const* d_in, const int* in_sizes, int n_in,
                              void* d_out, int out_size, void* d_ws, size_t ws_size,
                              hipStream_t stream) {
  const float* x     = (const float*)d_in[0];
  const float* Wg1   = (const float*)d_in[1];
  const float* Wg2   = (const float*)d_in[2];
  const float* Wup   = (const float*)d_in[3];
  const float* bup   = (const float*)d_in[4];
  const float* Wdown = (const float*)d_in[5];
  const float* bdown = (const float*)d_in[6];
  float* out = (float*)d_out;

  char* ws = (char*)d_ws;
  u16*   xb         = (u16*)(ws + OFF_XB);
  u16*   hbuf       = (u16*)(ws + OFF_H);
  u16*   slotbuf    = (u16*)(ws + OFF_SLOT);
  float* scr        = (float*)(ws + OFF_SCR);
  int*   eidx       = (int*)(ws + OFF_EIDX);
  int*   rows_slot  = (int*)(ws + OFF_RT);
  float* rowscore   = (float*)(ws + OFF_RS);
  int*   meta       = (int*)(ws + OFF_META);

  k_init<<<(MAXROWS + 255) / 256, 256, 0, stream>>>(meta, rows_slot, rowscore);
  k_gate<<<T_NUM / 16, 256, 0, stream>>>((const float4*)x, (const float4*)Wg1, Wg2,
                                         (ushort4*)xb, eidx, scr, meta);
  k_assign<<<TK_NUM / 256, 256, 0, stream>>>(eidx, scr, meta, rows_slot, rowscore);
  k_up<<<dim3(HE_DIM / TILE, MAXMT), 512, 0, stream>>>(xb, Wup, bup, meta, rows_slot, hbuf);
  k_down<<<dim3(D_DIM / TILE, MAXMT), 512, 0, stream>>>(hbuf, Wdown, bdown, meta,
                                                        rows_slot, rowscore, slotbuf);
  k_combine<<<T_NUM * D_DIM / 8 / 256, 256, 0, stream>>>(slotbuf, out);
}

// Round 7
// 363.021 us; speedup vs baseline: 1.1588x; 1.0813x over previous
//
#include <hip/hip_runtime.h>
#include <hip/hip_bf16.h>

// ---------------- problem constants ----------------
#define D_DIM 2048
#define HE_DIM 1024
#define E_NUM 8
#define T_NUM 4096
#define TK_NUM 8192           // T * K (top-2)
#define RTILE 64              // row (M) tile — 64 for 2x more blocks (occupancy lever)
#define NTILE 128             // col (N) tile
#define BK 64                 // K tile (proven conflict-free swizzle, 128B rows)
#define MAXROWS 8704          // TK + E*RTILE padding
#define MAXMT 136             // max m-tiles: 128 + 8

// meta (int) layout in workspace — counters padded to 128 B (32 ints).
#define M_CNT(e)  ((e) * 32)          // [0,256)   per-expert token count
#define M_FILL(e) (256 + (e) * 32)    // [256,512) atomic fill cursor
#define M_OFF  512                    // [8] padded row base per expert
#define M_NMT  520                    // [1] number of m-tiles
#define M_TE   528                    // [136] m-tile -> expert
#define M_TB   664                    // [136] m-tile -> global row base
#define M_TICKET 800                  // [1] gate last-block ticket
#define M_INTS 1024

typedef unsigned short u16;
typedef __attribute__((ext_vector_type(8))) short bf16x8;  // 8 bf16 in 4 VGPRs
typedef __attribute__((ext_vector_type(4))) float f32x4;

// workspace offsets (bytes)
// xb [0,16M) and wupb [16M,48M) are dead after k_up; slot [T][2][D] bf16 (33.5M)
// overlaps them (k_down/k_combine run strictly after k_up on the stream).
#define OFF_XB   ((size_t)0)                                     // [T][D] bf16  16 MB
#define OFF_WUPB (OFF_XB + (size_t)T_NUM * D_DIM * 2)            // [E][HE][D] bf16 32 MB
#define OFF_SLOT ((size_t)0)                                     // [T][2][D] bf16 33.5 MB (overlap)
#define OFF_WDNB (OFF_WUPB + (size_t)E_NUM * HE_DIM * D_DIM * 2) // [E][D][HE] bf16 32 MB
#define OFF_H    (OFF_WDNB + (size_t)E_NUM * D_DIM * HE_DIM * 2) // [MAXROWS][HE] bf16 17.8 MB
#define OFF_SCR  (OFF_H + (size_t)MAXROWS * HE_DIM * 2)          // [TK] f32 slot score
#define OFF_EIDX (OFF_SCR + (size_t)TK_NUM * 4)                  // [TK] int slot expert
#define OFF_RT   (OFF_EIDX + (size_t)TK_NUM * 4)                 // [MAXROWS] int row->slot id
#define OFF_RS   (OFF_RT + (size_t)MAXROWS * 4)                  // [MAXROWS] f32 row score
#define OFF_META (OFF_RS + (size_t)MAXROWS * 4)                  // ints

__device__ __forceinline__ u16 f2bf(float f) {
  unsigned u = __float_as_uint(f);
  u += 0x7FFFu + ((u >> 16) & 1u);   // round-to-nearest-even
  return (u16)(u >> 16);
}
__device__ __forceinline__ float bf_lo(unsigned u) { return __uint_as_float(u << 16); }
__device__ __forceinline__ float bf_hi(unsigned u) { return __uint_as_float(u & 0xFFFF0000u); }

__device__ __forceinline__ void gload16(const void* g, void* l) {
  // async global->LDS, 16B per lane; LDS dest = wave-uniform base + lane*16
  __builtin_amdgcn_global_load_lds((const __attribute__((address_space(1))) void*)g,
                                   (__attribute__((address_space(3))) void*)l,
                                   16, 0, 0);
}

// ---------------- f32 -> bf16 weight conversion + meta/rows init (one launch) ----------------
__global__ void k_cvt2(const float4* __restrict__ s1, const float4* __restrict__ s2,
                       ushort4* __restrict__ d1, ushort4* __restrict__ d2, int n4,
                       int* __restrict__ meta, int* __restrict__ rows_slot,
                       float* __restrict__ rowscore) {
  const int i0 = blockIdx.x * blockDim.x + threadIdx.x;
  if (i0 < M_INTS) meta[i0] = 0;
  if (i0 < MAXROWS) { rows_slot[i0] = -1; rowscore[i0] = 0.0f; }
  const int st = gridDim.x * blockDim.x;
  for (int i = i0; i < 2 * n4; i += st) {
    const float4* s = (i < n4) ? s1 : s2;
    ushort4* d = (i < n4) ? d1 : d2;
    int j = (i < n4) ? i : i - n4;
    float4 v = s[j];
    ushort4 o;
    o.x = f2bf(v.x); o.y = f2bf(v.y); o.z = f2bf(v.z); o.w = f2bf(v.w);
    d[j] = o;
  }
}

// ---------------- gate: Wg1 in LDS, LDS count histogram, padded global atomics ----------------
// Last block to finish (device ticket) also computes the offsets + tile map.
__global__ __launch_bounds__(256) void k_gate(
    const float4* __restrict__ x4, const float4* __restrict__ Wg1_4,
    const float* __restrict__ Wg2, ushort4* __restrict__ xb4,
    int* __restrict__ eidx, float* __restrict__ scr, int* __restrict__ meta) {
  __shared__ float4 wg1s[E_NUM * (D_DIM / 4)];   // 8*512*16B = 64 KB
  __shared__ int cnt_s[E_NUM];
  __shared__ int lastf;
  const int tid = threadIdx.x;
  if (tid < E_NUM) cnt_s[tid] = 0;
#pragma unroll
  for (int i = 0; i < 16; ++i) wg1s[tid + i * 256] = Wg1_4[tid + i * 256];
  __syncthreads();

  const int w = tid >> 6;
  const int lane = tid & 63;
  for (int j = 0; j < 4; ++j) {
    const int t = blockIdx.x * 16 + w * 4 + j;
    float acc[E_NUM];
#pragma unroll
    for (int e = 0; e < E_NUM; ++e) acc[e] = 0.f;
#pragma unroll
    for (int i = 0; i < 8; ++i) {
      const int c = lane + i * 64;                 // float4 index within row (0..511)
      float4 xv = x4[(size_t)t * 512 + c];
      ushort4 o;
      o.x = f2bf(xv.x); o.y = f2bf(xv.y); o.z = f2bf(xv.z); o.w = f2bf(xv.w);
      xb4[(size_t)t * 512 + c] = o;
#pragma unroll
      for (int e = 0; e < E_NUM; ++e) {
        float4 wv = wg1s[e * 512 + c];
        acc[e] += xv.x * wv.x + xv.y * wv.y + xv.z * wv.z + xv.w * wv.w;
      }
    }
#pragma unroll
    for (int e = 0; e < E_NUM; ++e) {
      float v = acc[e];
#pragma unroll
      for (int off = 32; off; off >>= 1) v += __shfl_xor(v, off, 64);
      acc[e] = v;
    }
    if (lane == 0) {
      float l1[E_NUM], lg[E_NUM];
#pragma unroll
      for (int e = 0; e < E_NUM; ++e) l1[e] = tanhf(acc[e]);
#pragma unroll
      for (int i = 0; i < E_NUM; ++i) {
        float s = 0.f;
#pragma unroll
        for (int e = 0; e < E_NUM; ++e) s += l1[e] * Wg2[i * E_NUM + e];
        lg[i] = s;
      }
      // stable top-2 (lowest index wins ties, like jax.lax.top_k)
      int i0 = 0; float v0 = lg[0];
#pragma unroll
      for (int i = 1; i < E_NUM; ++i) if (lg[i] > v0) { v0 = lg[i]; i0 = i; }
      int i1 = -1; float v1 = -3.4e38f;
#pragma unroll
      for (int i = 0; i < E_NUM; ++i) if (i != i0 && lg[i] > v1) { v1 = lg[i]; i1 = i; }
      float e1 = __expf(v1 - v0);
      float s0 = 1.f / (1.f + e1);
      float s1 = e1 * s0;
      eidx[t * 2] = i0; eidx[t * 2 + 1] = i1;
      scr[t * 2] = s0;  scr[t * 2 + 1] = s1;
      atomicAdd(&cnt_s[i0], 1);      // LDS atomic — block-local, cheap
      atomicAdd(&cnt_s[i1], 1);
    }
  }
  __syncthreads();
  if (tid < E_NUM) atomicAdd(&meta[M_CNT(tid)], cnt_s[tid]);  // 8/block, padded lines

  // ---- last-block-done: compute offsets + tile map ----
  if (tid == 0) {
    __threadfence();
    lastf = (atomicAdd(&meta[M_TICKET], 1) == (int)gridDim.x - 1);
  }
  __syncthreads();
  if (lastf && tid < 64) {
    const int l2 = tid;
    int cnt = (l2 < E_NUM) ? atomicAdd(&meta[M_CNT(l2)], 0) : 0;
    int tiles = (cnt + RTILE - 1) / RTILE;
    int pre = tiles;
#pragma unroll
    for (int off = 1; off < E_NUM; off <<= 1) {
      int v = __shfl_up(pre, off, 64);
      if (l2 >= off && l2 < E_NUM) pre += v;
    }
    int tb_excl = pre - tiles;               // exclusive prefix (valid lanes 0..7)
    if (l2 < E_NUM) meta[M_OFF + l2] = tb_excl * RTILE;
    const int nmt = __shfl(pre, E_NUM - 1, 64);
    if (l2 == 0) meta[M_NMT] = nmt;
    int tb[E_NUM];
#pragma unroll
    for (int k = 0; k < E_NUM; ++k) tb[k] = __shfl(tb_excl, k, 64);
    for (int mt = l2; mt < nmt; mt += 64) {
      int e = 0;
#pragma unroll
      for (int k = 1; k < E_NUM; ++k) if (mt >= tb[k]) e = k;
      meta[M_TE + mt] = e;
      meta[M_TB + mt] = mt * RTILE;          // tile bases are contiguous multiples of RTILE
    }
  }
}

// ---------------- compaction: wave-aggregated fetch-add ----------------
__global__ void k_assign(const int* __restrict__ eidx, const float* __restrict__ scr,
                         int* __restrict__ meta, int* __restrict__ rows_slot,
                         float* __restrict__ rowscore) {
  int i = blockIdx.x * blockDim.x + threadIdx.x;
  const int lane = threadIdx.x & 63;
  int e = eidx[i];
  int pos = 0;
#pragma unroll
  for (int ex = 0; ex < E_NUM; ++ex) {
    unsigned long long m = __ballot(e == ex);
    if (e == ex) {
      int leader = __ffsll((long long)m) - 1;
      int rank = __popcll(m & ((1ull << lane) - 1ull));
      int b = 0;
      if (lane == leader) b = atomicAdd(&meta[M_FILL(ex)], __popcll(m));
      b = __shfl(b, leader, 64);
      pos = b + rank;
    }
  }
  int r = meta[M_OFF + e] + pos;
  rows_slot[r] = i;            // slot id (token = i>>1)
  rowscore[r] = scr[i];
}

// ---------------- grouped up-GEMM: h = silu(Xg @ Wup[e]^T + bup[e]) ----------------
// 64x128 tile, 256 threads / 4 waves (each 32x64, acc[2][4]); 2 LDS buffers =
// 48 KB -> 3 blocks/CU resident; grid 8 x 136 = 1088 blocks (~4/CU dispatched).
// Independent co-resident blocks are the proven latency hider here (r1 vs r3/r5
// A/B; m102 shape curve). Inner loop identical to r1's proven conflict-free
// structure: XOR swizzle on global src addr, linear gload_lds dest, drain at
// __syncthreads.
__global__ __launch_bounds__(256) void k_up(
    const u16* __restrict__ xb, const u16* __restrict__ wupb,
    const float* __restrict__ bup, const int* __restrict__ meta,
    const int* __restrict__ rows_slot, u16* __restrict__ hbuf) {
  const int mt = blockIdx.y;
  if (mt >= meta[M_NMT]) return;
  const int e = meta[M_TE + mt];
  const int mbase = meta[M_TB + mt];
  const int nt = blockIdx.x;

  __shared__ u16 As[2][RTILE * BK];   // 2 x 8 KB
  __shared__ u16 Bs[2][NTILE * BK];   // 2 x 16 KB

  const int tid = threadIdx.x;
  const int lane = tid & 63;
  const int w = tid >> 6;                                // 0..3
  const int r0 = tid >> 3;                               // staged row 0..31
  const int cb = (((tid & 7) ^ (r0 & 7)) * 8);           // swizzled k-chunk (elements)

  const u16* gA[2];
  const u16* gB[4];
#pragma unroll
  for (int j = 0; j < 2; ++j) {
    int s = rows_slot[mbase + r0 + 32 * j]; if (s < 0) s = 0;
    gA[j] = xb + (size_t)(s >> 1) * D_DIM + cb;
  }
#pragma unroll
  for (int j = 0; j < 4; ++j)
    gB[j] = wupb + ((size_t)e * HE_DIM + nt * NTILE + r0 + 32 * j) * D_DIM + cb;

  const int wm = (w & 1) * 32;
  const int wn = (w >> 1) * 64;
  const int quad = lane >> 4;
  const int l16 = lane & 15;
  const int sw = l16 & 7;

  f32x4 acc[2][4] = {};

#define STAGE_UP(buf, k0) \
  { gload16(gA[0] + (k0), &As[buf][tid * 8]);        \
    gload16(gA[1] + (k0), &As[buf][tid * 8 + 2048]); \
    gload16(gB[0] + (k0), &Bs[buf][tid * 8]);        \
    gload16(gB[1] + (k0), &Bs[buf][tid * 8 + 2048]); \
    gload16(gB[2] + (k0), &Bs[buf][tid * 8 + 4096]); \
    gload16(gB[3] + (k0), &Bs[buf][tid * 8 + 6144]); }

  STAGE_UP(0, 0);
  __syncthreads();                      // tile 0 resident
  int cur = 0;
  for (int k0 = 0; k0 < D_DIM; k0 += BK) {
    if (k0 + BK < D_DIM) STAGE_UP(cur ^ 1, k0 + BK);   // prefetch next tile
    const u16* pa0 = &As[cur][(wm + l16) * BK];
    const u16* pb0 = &Bs[cur][(wn + l16) * BK];
#pragma unroll
    for (int h = 0; h < 2; ++h) {
      const int off = ((h * 4 + quad) ^ sw) * 8;
      bf16x8 af[2], bfr[4];
#pragma unroll
      for (int i = 0; i < 2; ++i) af[i] = *(const bf16x8*)(pa0 + i * 16 * BK + off);
#pragma unroll
      for (int i = 0; i < 4; ++i) bfr[i] = *(const bf16x8*)(pb0 + i * 16 * BK + off);
#pragma unroll
      for (int mi = 0; mi < 2; ++mi)
#pragma unroll
        for (int ni = 0; ni < 4; ++ni)
          acc[mi][ni] = __builtin_amdgcn_mfma_f32_16x16x32_bf16(af[mi], bfr[ni], acc[mi][ni], 0, 0, 0);
    }
    __syncthreads();                    // drains prefetch + LDS read completion
    cur ^= 1;
  }

#pragma unroll
  for (int mi = 0; mi < 2; ++mi) {
    const int m = wm + mi * 16 + quad * 4;
#pragma unroll
    for (int ni = 0; ni < 4; ++ni) {
      const int ng = nt * NTILE + wn + ni * 16 + l16;
      const float bias = bup[e * HE_DIM + ng];
#pragma unroll
      for (int r = 0; r < 4; ++r) {
        float v = acc[mi][ni][r] + bias;
        v = v / (1.0f + __expf(-v));     // silu
        hbuf[(size_t)(mbase + m + r) * HE_DIM + ng] = f2bf(v);
      }
    }
  }
}

// ---------------- grouped down-GEMM: slot[s] = score * (h @ Wdown[e]^T + bdown[e]) ----------------
__global__ __launch_bounds__(256) void k_down(
    const u16* __restrict__ hbuf, const u16* __restrict__ wdnb,
    const float* __restrict__ bdown, const int* __restrict__ meta,
    const int* __restrict__ rows_slot, const float* __restrict__ rowscore,
    u16* __restrict__ slot) {
  const int mt = blockIdx.y;
  if (mt >= meta[M_NMT]) return;
  const int e = meta[M_TE + mt];
  const int mbase = meta[M_TB + mt];
  const int nt = blockIdx.x;

  __shared__ u16 As[2][RTILE * BK];
  __shared__ u16 Bs[2][NTILE * BK];

  const int tid = threadIdx.x;
  const int lane = tid & 63;
  const int w = tid >> 6;
  const int r0 = tid >> 3;
  const int cb = (((tid & 7) ^ (r0 & 7)) * 8);

  const u16* gA[2];
  const u16* gB[4];
#pragma unroll
  for (int j = 0; j < 2; ++j)
    gA[j] = hbuf + (size_t)(mbase + r0 + 32 * j) * HE_DIM + cb;
#pragma unroll
  for (int j = 0; j < 4; ++j)
    gB[j] = wdnb + ((size_t)e * D_DIM + nt * NTILE + r0 + 32 * j) * HE_DIM + cb;

  const int wm = (w & 1) * 32;
  const int wn = (w >> 1) * 64;
  const int quad = lane >> 4;
  const int l16 = lane & 15;
  const int sw = l16 & 7;

  f32x4 acc[2][4] = {};

#define STAGE_DN(buf, k0) \
  { gload16(gA[0] + (k0), &As[buf][tid * 8]);        \
    gload16(gA[1] + (k0), &As[buf][tid * 8 + 2048]); \
    gload16(gB[0] + (k0), &Bs[buf][tid * 8]);        \
    gload16(gB[1] + (k0), &Bs[buf][tid * 8 + 2048]); \
    gload16(gB[2] + (k0), &Bs[buf][tid * 8 + 4096]); \
    gload16(gB[3] + (k0), &Bs[buf][tid * 8 + 6144]); }

  STAGE_DN(0, 0);
  __syncthreads();
  int cur = 0;
  for (int k0 = 0; k0 < HE_DIM; k0 += BK) {
    if (k0 + BK < HE_DIM) STAGE_DN(cur ^ 1, k0 + BK);
    const u16* pa0 = &As[cur][(wm + l16) * BK];
    const u16* pb0 = &Bs[cur][(wn + l16) * BK];
#pragma unroll
    for (int h = 0; h < 2; ++h) {
      const int off = ((h * 4 + quad) ^ sw) * 8;
      bf16x8 af[2], bfr[4];
#pragma unroll
      for (int i = 0; i < 2; ++i) af[i] = *(const bf16x8*)(pa0 + i * 16 * BK + off);
#pragma unroll
      for (int i = 0; i < 4; ++i) bfr[i] = *(const bf16x8*)(pb0 + i * 16 * BK + off);
#pragma unroll
      for (int mi = 0; mi < 2; ++mi)
#pragma unroll
        for (int ni = 0; ni < 4; ++ni)
          acc[mi][ni] = __builtin_amdgcn_mfma_f32_16x16x32_bf16(af[mi], bfr[ni], acc[mi][ni], 0, 0, 0);
    }
    __syncthreads();
    cur ^= 1;
  }

#pragma unroll
  for (int mi = 0; mi < 2; ++mi) {
    const int m = wm + mi * 16 + quad * 4;
#pragma unroll
    for (int r = 0; r < 4; ++r) {
      const int rg = mbase + m + r;
      const int s = rows_slot[rg];
      const float sc = rowscore[rg];
      if (s < 0) continue;               // padding row
      u16* dst = slot + (size_t)s * D_DIM;
#pragma unroll
      for (int ni = 0; ni < 4; ++ni) {
        const int ng = nt * NTILE + wn + ni * 16 + l16;
        float v = (acc[mi][ni][r] + bdown[e * D_DIM + ng]) * sc;
        dst[ng] = f2bf(v);
      }
    }
  }
}

// ---------------- combine: out[t] = slot[t][0] + slot[t][1] (fully coalesced) ----------------
__global__ __launch_bounds__(256) void k_combine(const u16* __restrict__ slot,
                                                 float* __restrict__ out) {
  int i = blockIdx.x * blockDim.x + threadIdx.x;   // one 16B chunk (8 bf16) per thread
  int t = i >> 8;                                  // D/8 = 256 chunks per token
  int c = i & 255;
  const uint4* p0 = (const uint4*)(slot + (size_t)(t * 2) * D_DIM) + c;
  const uint4* p1 = (const uint4*)(slot + (size_t)(t * 2 + 1) * D_DIM) + c;
  uint4 a = *p0, b = *p1;
  float4 o0, o1;
  o0.x = bf_lo(a.x) + bf_lo(b.x);  o0.y = bf_hi(a.x) + bf_hi(b.x);
  o0.z = bf_lo(a.y) + bf_lo(b.y);  o0.w = bf_hi(a.y) + bf_hi(b.y);
  o1.x = bf_lo(a.z) + bf_lo(b.z);  o1.y = bf_hi(a.z) + bf_hi(b.z);
  o1.z = bf_lo(a.w) + bf_lo(b.w);  o1.w = bf_hi(a.w) + bf_hi(b.w);
  float4* po = (float4*)(out + (size_t)t * D_DIM) + c * 2;
  po[0] = o0;
  po[1] = o1;
}

// ---------------- launcher ----------------
extern "C" void kernel_launch(void* const* d_in, const int* in_sizes, int n_in,
                              void* d_out, int out_size, void* d_ws, size_t ws_size,
                              hipStream_t stream) {
  const float* x     = (const float*)d_in[0];
  const float* Wg1   = (const float*)d_in[1];
  const float* Wg2   = (const float*)d_in[2];
  const float* Wup   = (const float*)d_in[3];
  const float* bup   = (const float*)d_in[4];
  const float* Wdown = (const float*)d_in[5];
  const float* bdown = (const float*)d_in[6];
  float* out = (float*)d_out;

  char* ws = (char*)d_ws;
  u16*   xb         = (u16*)(ws + OFF_XB);
  u16*   wupb       = (u16*)(ws + OFF_WUPB);
  u16*   wdnb       = (u16*)(ws + OFF_WDNB);
  u16*   hbuf       = (u16*)(ws + OFF_H);
  u16*   slotbuf    = (u16*)(ws + OFF_SLOT);
  float* scr        = (float*)(ws + OFF_SCR);
  int*   eidx       = (int*)(ws + OFF_EIDX);
  int*   rows_slot  = (int*)(ws + OFF_RT);
  float* rowscore   = (float*)(ws + OFF_RS);
  int*   meta       = (int*)(ws + OFF_META);

  k_cvt2<<<8192, 256, 0, stream>>>((const float4*)Wup, (const float4*)Wdown,
                                   (ushort4*)wupb, (ushort4*)wdnb,
                                   E_NUM * HE_DIM * D_DIM / 4,
                                   meta, rows_slot, rowscore);
  k_gate<<<T_NUM / 16, 256, 0, stream>>>((const float4*)x, (const float4*)Wg1, Wg2,
                                         (ushort4*)xb, eidx, scr, meta);
  k_assign<<<TK_NUM / 256, 256, 0, stream>>>(eidx, scr, meta, rows_slot, rowscore);
  k_up<<<dim3(HE_DIM / NTILE, MAXMT), 256, 0, stream>>>(xb, wupb, bup, meta, rows_slot, hbuf);
  k_down<<<dim3(D_DIM / NTILE, MAXMT), 256, 0, stream>>>(hbuf, wdnb, bdown, meta,
                                                         rows_slot, rowscore, slotbuf);
  k_combine<<<T_NUM * D_DIM / 8 / 256, 256, 0, stream>>>(slotbuf, out);
}